// Round 3
// baseline (553.873 us; speedup 1.0000x reference)
//
#include <hip/hip_runtime.h>
#include <cstddef>

#define LSEQ    1024
#define DMODEL  256
#define DINNER  512
#define DSTATE  64
#define NHEADS  8
#define HEADDIM 64
#define CONVDIM 640
#define DINPROJ 1160
#define ROWS    2048   // B * L
#define EPSF    1e-5f
#define NC      16     // chunks per sequence
#define LC      64     // chunk length
#define XBCW    648    // xBC (640) + raw dt (8)

__device__ __forceinline__ float sigmoidf_(float x) { return 1.0f / (1.0f + expf(-x)); }
__device__ __forceinline__ float siluf_(float x)    { return x / (1.0f + expf(-x)); }
__device__ __forceinline__ float softplusf_(float x) {
    return x > 0.0f ? x + log1pf(expf(-x)) : log1pf(expf(x));
}

// ---------------------------------------------------------------- embedding
__global__ __launch_bounds__(256) void embed_kernel(
    const int* __restrict__ ids, const float* __restrict__ mask,
    const float* __restrict__ tok, const float* __restrict__ pos,
    float* __restrict__ u0, float* __restrict__ u1) {
    int row = blockIdx.x;            // b*1024 + t
    int d = threadIdx.x;
    int b = row >> 10, t = row & 1023;
    int id = ids[row];
    float v = tok[(size_t)id * DMODEL + d] + pos[(size_t)t * DMODEL + d];
    v *= mask[row];
    u0[(size_t)row * DMODEL + d] = v;
    u1[((size_t)(b << 10) + (1023 - t)) * DMODEL + d] = v;   // time-flipped copy
}

// ---------------------------------------------------------------- big-tile GEMM  C = A[M,K]*W[N,K]^T  (128x128, 8x8 micro)
#define GPAD 4
#define FMA4(accv, a_s, bv) { accv.x = fmaf(a_s, bv.x, accv.x); accv.y = fmaf(a_s, bv.y, accv.y); \
                              accv.z = fmaf(a_s, bv.z, accv.z); accv.w = fmaf(a_s, bv.w, accv.w); }
__global__ __launch_bounds__(256) void gemm128(
    const float* __restrict__ A, const float* __restrict__ W,
    float* __restrict__ C0, float* __restrict__ C1,
    int M, int N, int K, int Nsplit, int ld0, int ld1,
    long sA, long sW, long sC0, long sC1) {
    int dir = blockIdx.z;
    A += (size_t)dir * sA; W += (size_t)dir * sW;
    C0 += (size_t)dir * sC0; C1 += (size_t)dir * sC1;
    __shared__ float As[16][128 + GPAD];
    __shared__ float Bs[16][128 + GPAD];
    int tid = threadIdx.x;
    int tx = tid & 15, ty = tid >> 4;
    int m0 = blockIdx.x * 128, n0 = blockIdx.y * 128;
    int arow = tid & 127, aseg = tid >> 7;        // aseg: which 8-wide k half
    float4 acc[2][4][2];
#pragma unroll
    for (int rg = 0; rg < 2; ++rg)
#pragma unroll
        for (int i = 0; i < 4; ++i)
#pragma unroll
            for (int cg = 0; cg < 2; ++cg) acc[rg][i][cg] = make_float4(0.f, 0.f, 0.f, 0.f);

    for (int k0 = 0; k0 < K; k0 += 16) {
        const float* Ap = &A[(size_t)(m0 + arow) * K + k0 + aseg * 8];
        float4 av0 = *(const float4*)Ap;
        float4 av1 = *(const float4*)(Ap + 4);
        int bj = n0 + arow;
        float4 bv0 = make_float4(0.f, 0.f, 0.f, 0.f), bv1 = bv0;
        if (bj < N) {
            const float* Wp = &W[(size_t)bj * K + k0 + aseg * 8];
            bv0 = *(const float4*)Wp;
            bv1 = *(const float4*)(Wp + 4);
        }
        int kb = aseg * 8;
        As[kb + 0][arow] = av0.x; As[kb + 1][arow] = av0.y; As[kb + 2][arow] = av0.z; As[kb + 3][arow] = av0.w;
        As[kb + 4][arow] = av1.x; As[kb + 5][arow] = av1.y; As[kb + 6][arow] = av1.z; As[kb + 7][arow] = av1.w;
        Bs[kb + 0][arow] = bv0.x; Bs[kb + 1][arow] = bv0.y; Bs[kb + 2][arow] = bv0.z; Bs[kb + 3][arow] = bv0.w;
        Bs[kb + 4][arow] = bv1.x; Bs[kb + 5][arow] = bv1.y; Bs[kb + 6][arow] = bv1.z; Bs[kb + 7][arow] = bv1.w;
        __syncthreads();
#pragma unroll
        for (int k = 0; k < 16; ++k) {
            float4 a0 = *(const float4*)&As[k][ty * 4];
            float4 a1 = *(const float4*)&As[k][64 + ty * 4];
            float4 b0 = *(const float4*)&Bs[k][tx * 4];
            float4 b1 = *(const float4*)&Bs[k][64 + tx * 4];
            float ar[2][4] = {{a0.x, a0.y, a0.z, a0.w}, {a1.x, a1.y, a1.z, a1.w}};
#pragma unroll
            for (int rg = 0; rg < 2; ++rg)
#pragma unroll
                for (int i = 0; i < 4; ++i) {
                    FMA4(acc[rg][i][0], ar[rg][i], b0);
                    FMA4(acc[rg][i][1], ar[rg][i], b1);
                }
        }
        __syncthreads();
    }
#pragma unroll
    for (int rg = 0; rg < 2; ++rg)
#pragma unroll
        for (int i = 0; i < 4; ++i) {
            int m = m0 + rg * 64 + ty * 4 + i;
#pragma unroll
            for (int cg = 0; cg < 2; ++cg) {
                int n = n0 + cg * 64 + tx * 4;
                if (n < N) {   // N multiple of 4, float4 never straddles
                    if (n < Nsplit) *(float4*)&C0[(size_t)m * ld0 + n] = acc[rg][i][cg];
                    else            *(float4*)&C1[(size_t)m * ld1 + (n - Nsplit)] = acc[rg][i][cg];
                }
            }
        }
}

// ---------------------------------------------------------------- small GEMM (64x64, 4x4 micro) for out_proj / fusion
#define BM 64
#define BN 64
#define BKK 16
__global__ __launch_bounds__(256) void gemm_nt(
    const float* __restrict__ A, const float* __restrict__ W,
    float* __restrict__ C0, float* __restrict__ C1,
    int M, int N, int K, int Nsplit, int ld0, int ld1,
    long sA, long sW, long sC0, long sC1) {
    int dir = blockIdx.z;
    A += (size_t)dir * sA; W += (size_t)dir * sW;
    C0 += (size_t)dir * sC0; C1 += (size_t)dir * sC1;
    __shared__ float As[BKK][BM + 8];
    __shared__ float Bs[BKK][BN + 8];
    int tid = threadIdx.x;
    int tx = tid & 15, ty = tid >> 4;
    int m0 = blockIdx.x * BM, n0 = blockIdx.y * BN;
    float acc[4][4] = {{0.f}};
    int srow = tid >> 2, sseg = tid & 3;

    for (int k0 = 0; k0 < K; k0 += BKK) {
        float4 av = *(const float4*)&A[(size_t)(m0 + srow) * K + k0 + sseg * 4];
        As[sseg * 4 + 0][srow] = av.x; As[sseg * 4 + 1][srow] = av.y;
        As[sseg * 4 + 2][srow] = av.z; As[sseg * 4 + 3][srow] = av.w;
        int bj = n0 + srow;
        float4 bv = make_float4(0.f, 0.f, 0.f, 0.f);
        if (bj < N) bv = *(const float4*)&W[(size_t)bj * K + k0 + sseg * 4];
        Bs[sseg * 4 + 0][srow] = bv.x; Bs[sseg * 4 + 1][srow] = bv.y;
        Bs[sseg * 4 + 2][srow] = bv.z; Bs[sseg * 4 + 3][srow] = bv.w;
        __syncthreads();
#pragma unroll
        for (int k = 0; k < BKK; ++k) {
            float4 a4 = *(const float4*)&As[k][ty * 4];
            float4 b4 = *(const float4*)&Bs[k][tx * 4];
            float a_[4] = {a4.x, a4.y, a4.z, a4.w};
            float b_[4] = {b4.x, b4.y, b4.z, b4.w};
#pragma unroll
            for (int i = 0; i < 4; ++i)
#pragma unroll
                for (int j = 0; j < 4; ++j) acc[i][j] = fmaf(a_[i], b_[j], acc[i][j]);
        }
        __syncthreads();
    }
#pragma unroll
    for (int i = 0; i < 4; ++i) {
        int m = m0 + ty * 4 + i;
#pragma unroll
        for (int j = 0; j < 4; ++j) {
            int n = n0 + tx * 4 + j;
            if (n < N) {
                if (n < Nsplit) C0[(size_t)m * ld0 + n] = acc[i][j];
                else            C1[(size_t)m * ld1 + (n - Nsplit)] = acc[i][j];
            }
        }
    }
}

// ---------------------------------------------------------------- depthwise causal conv(4) + SiLU, plus softplus(dt)
__global__ __launch_bounds__(256) void conv_dt_kernel(
    const float* __restrict__ xbc, float* __restrict__ xc, float* __restrict__ dts,
    const float* __restrict__ cw, const float* __restrict__ cb,
    const float* __restrict__ dtb, int layer) {
    int row = blockIdx.x;            // b*1024+t
    int dir = blockIdx.y;
    int b = row >> 10, t = row & 1023;
    const float* xd = xbc + (size_t)dir * ROWS * XBCW;
    int pi = dir * 2 + layer;
    const float* cwl = cw + (size_t)pi * CONVDIM * 4;
    const float* cbl = cb + (size_t)pi * CONVDIM;
    const float* dtbl = dtb + pi * NHEADS;
    for (int c = threadIdx.x; c < CONVDIM + NHEADS; c += 256) {
        if (c < CONVDIM) {
            float acc = cbl[c];
#pragma unroll
            for (int k = 0; k < 4; ++k) {
                int tt = t - 3 + k;
                if (tt >= 0)
                    acc = fmaf(xd[(size_t)((b << 10) + tt) * XBCW + c], cwl[c * 4 + k], acc);
            }
            xc[((size_t)dir * ROWS + row) * CONVDIM + c] = siluf_(acc);
        } else {
            int hh = c - CONVDIM;
            dts[((size_t)dir * ROWS + row) * NHEADS + hh] =
                softplusf_(xd[(size_t)row * XBCW + CONVDIM + hh] + dtbl[hh]);
        }
    }
}

// ---------------------------------------------------------------- S1: local chunk scan (from zero state), latency-hoisted
__global__ __launch_bounds__(64) void scan_chunk_kernel(
    const float* __restrict__ xc, const float* __restrict__ dts,
    float* __restrict__ y, const float* __restrict__ Alog, const float* __restrict__ Dp,
    float* __restrict__ H, float* __restrict__ cumb, int layer) {
    __shared__ float sBC[LC * 128];
    __shared__ float sX[LC * 64];
    int blk = blockIdx.x;
    int u = blk >> 4, c = blk & 15;
    int dir = u >> 4, b = (u >> 3) & 1, h = u & 7;
    int p = threadIdx.x;
    int pi = dir * 2 + layer;
    float Av = -expf(Alog[pi * NHEADS + h]);
    float Dv = Dp[pi * NHEADS + h];
    const float* xcd = xc + (size_t)dir * ROWS * CONVDIM;
    const float* dtd = dts + (size_t)dir * ROWS * NHEADS;
    float* yd = y + (size_t)dir * ROWS * DINNER;
    int t0 = c * LC, base = b << 10;

    // lane t holds dt / dA for step t of this chunk (single coalesced-ish load + one wave-wide expf)
    float dt_l = dtd[(size_t)(base + t0 + p) * NHEADS + h];
    float dA_l = expf(dt_l * Av);
    // inclusive prefix product of dA across lanes -> cum[t]
    float cum_l = dA_l;
#pragma unroll
    for (int off = 1; off < 64; off <<= 1) {
        float o = __shfl_up(cum_l, off);
        if (p >= off) cum_l *= o;
    }
    cumb[(u << 10) + t0 + p] = cum_l;

    // stage B/C (xc cols 512..639): 64 rows x 128 floats
#pragma unroll
    for (int j = 0; j < 32; ++j) {
        int f4 = j * 64 + p;
        int trow = f4 >> 5, col4 = f4 & 31;
        float4 v = *(const float4*)&xcd[(size_t)(base + t0 + trow) * CONVDIM + DINNER + col4 * 4];
        *(float4*)&sBC[trow * 128 + col4 * 4] = v;
    }
    // stage x head-slice: 64 rows x 64 floats
#pragma unroll
    for (int j = 0; j < 16; ++j) {
        int f4 = j * 64 + p;
        int trow = f4 >> 4, col4 = f4 & 15;
        float4 v = *(const float4*)&xcd[(size_t)(base + t0 + trow) * CONVDIM + h * HEADDIM + col4 * 4];
        *(float4*)&sX[trow * 64 + col4 * 4] = v;
    }
    __syncthreads();

    float hreg[DSTATE];
#pragma unroll
    for (int n = 0; n < DSTATE; ++n) hreg[n] = 0.f;

#pragma unroll 2
    for (int tt = 0; tt < LC; ++tt) {
        float dtv = __shfl(dt_l, tt);
        float dA  = __shfl(dA_l, tt);
        float xv = sX[tt * 64 + p];
        float coef = dtv * xv;
        const float* Bsr = &sBC[tt * 128];
        const float* Csr = Bsr + 64;
        float y0 = 0.f, y1 = 0.f, y2 = 0.f, y3 = 0.f;
#pragma unroll
        for (int n = 0; n < DSTATE; n += 4) {
            float4 b4 = *(const float4*)&Bsr[n];
            float4 c4 = *(const float4*)&Csr[n];
            hreg[n]     = fmaf(hreg[n],     dA, coef * b4.x); y0 = fmaf(hreg[n],     c4.x, y0);
            hreg[n + 1] = fmaf(hreg[n + 1], dA, coef * b4.y); y1 = fmaf(hreg[n + 1], c4.y, y1);
            hreg[n + 2] = fmaf(hreg[n + 2], dA, coef * b4.z); y2 = fmaf(hreg[n + 2], c4.z, y2);
            hreg[n + 3] = fmaf(hreg[n + 3], dA, coef * b4.w); y3 = fmaf(hreg[n + 3], c4.w, y3);
        }
        yd[(size_t)(base + t0 + tt) * DINNER + h * HEADDIM + p] = (y0 + y1) + (y2 + y3) + Dv * xv;
    }
    float* Hb = H + (size_t)blk * 4096 + p * 64;
#pragma unroll
    for (int n = 0; n < DSTATE; n += 4)
        *(float4*)&Hb[n] = make_float4(hreg[n], hreg[n + 1], hreg[n + 2], hreg[n + 3]);
}

// ---------------------------------------------------------------- S2: carry chain over chunks (in place: h_end -> h_in)
__global__ __launch_bounds__(256) void carry_kernel(
    float* __restrict__ H, const float* __restrict__ cumb) {
    int u = blockIdx.x;
    int tid = threadIdx.x;
    float P[NC];
#pragma unroll
    for (int c = 0; c < NC; ++c) P[c] = cumb[(u << 10) + c * LC + (LC - 1)];
    float carry[16];
#pragma unroll
    for (int j = 0; j < 16; ++j) carry[j] = 0.f;
    float4 e[4];
    {
        float* Hb = H + (size_t)(u * NC) * 4096 + tid * 16;
#pragma unroll
        for (int j = 0; j < 4; ++j) e[j] = *(const float4*)&Hb[j * 4];
    }
    for (int c = 0; c < NC; ++c) {
        float4 en[4];
        if (c + 1 < NC) {
            float* Hn = H + (size_t)(u * NC + c + 1) * 4096 + tid * 16;
#pragma unroll
            for (int j = 0; j < 4; ++j) en[j] = *(const float4*)&Hn[j * 4];
        }
        float* Hb = H + (size_t)(u * NC + c) * 4096 + tid * 16;
        float Pc = P[c];
#pragma unroll
        for (int j = 0; j < 4; ++j) {
            *(float4*)&Hb[j * 4] = make_float4(carry[j * 4], carry[j * 4 + 1], carry[j * 4 + 2], carry[j * 4 + 3]);
            carry[j * 4]     = fmaf(Pc, carry[j * 4],     e[j].x);
            carry[j * 4 + 1] = fmaf(Pc, carry[j * 4 + 1], e[j].y);
            carry[j * 4 + 2] = fmaf(Pc, carry[j * 4 + 2], e[j].z);
            carry[j * 4 + 3] = fmaf(Pc, carry[j * 4 + 3], e[j].w);
        }
#pragma unroll
        for (int j = 0; j < 4; ++j) e[j] = en[j];
    }
}

// ---------------------------------------------------------------- S3: y[t] += cum[t] * (C_t . h_in), chunks 1..NC-1
__global__ __launch_bounds__(64) void fix_kernel(
    const float* __restrict__ xc, float* __restrict__ y,
    const float* __restrict__ H, const float* __restrict__ cumb) {
    __shared__ float sC[LC * 64];
    int blk = blockIdx.x;
    int u = blk / (NC - 1);
    int c = blk % (NC - 1) + 1;
    int dir = u >> 4, b = (u >> 3) & 1, h = u & 7;
    int p = threadIdx.x;
    const float* xcd = xc + (size_t)dir * ROWS * CONVDIM;
    float* yd = y + (size_t)dir * ROWS * DINNER;
    int t0 = c * LC, base = b << 10;
    float cum_l = cumb[(u << 10) + t0 + p];   // lane t holds cum[t]
#pragma unroll
    for (int j = 0; j < 16; ++j) {
        int f4 = j * 64 + p;
        int trow = f4 >> 4, col4 = f4 & 15;
        float4 v = *(const float4*)&xcd[(size_t)(base + t0 + trow) * CONVDIM + DINNER + DSTATE + col4 * 4];
        *(float4*)&sC[trow * 64 + col4 * 4] = v;
    }
    const float* Hb = H + (size_t)(u * NC + c) * 4096 + p * 64;
    float hin[DSTATE];
#pragma unroll
    for (int n = 0; n < DSTATE; n += 4) {
        float4 v = *(const float4*)&Hb[n];
        hin[n] = v.x; hin[n + 1] = v.y; hin[n + 2] = v.z; hin[n + 3] = v.w;
    }
    __syncthreads();
#pragma unroll 2
    for (int tt = 0; tt < LC; ++tt) {
        float cumt = __shfl(cum_l, tt);
        const float* Cs = &sC[tt * 64];
        float y0 = 0.f, y1 = 0.f, y2 = 0.f, y3 = 0.f;
#pragma unroll
        for (int n = 0; n < DSTATE; n += 4) {
            y0 = fmaf(hin[n],     Cs[n],     y0);
            y1 = fmaf(hin[n + 1], Cs[n + 1], y1);
            y2 = fmaf(hin[n + 2], Cs[n + 2], y2);
            y3 = fmaf(hin[n + 3], Cs[n + 3], y3);
        }
        size_t yi = (size_t)(base + t0 + tt) * DINNER + h * HEADDIM + p;
        yd[yi] += cumt * ((y0 + y1) + (y2 + y3));
    }
}

// ---------------------------------------------------------------- y * silu(z), RMSNorm * norm_w   (in place on y)
__global__ __launch_bounds__(256) void gate_rms_kernel(
    float* __restrict__ y, const float* __restrict__ zbuf,
    const float* __restrict__ nw, int layer) {
    int row = blockIdx.x;
    int dir = blockIdx.y;
    const float* zrow = zbuf + ((size_t)dir * ROWS + row) * DINNER;
    float* yrow = y + ((size_t)dir * ROWS + row) * DINNER;
    const float* nwl = nw + (dir * 2 + layer) * DINNER;
    int tid = threadIdx.x;
    int i0 = tid, i1 = tid + 256;
    float g0 = yrow[i0] * siluf_(zrow[i0]);
    float g1 = yrow[i1] * siluf_(zrow[i1]);
    __shared__ float red[256];
    red[tid] = fmaf(g0, g0, g1 * g1);
    __syncthreads();
    for (int s = 128; s > 0; s >>= 1) {
        if (tid < s) red[tid] += red[tid + s];
        __syncthreads();
    }
    float scale = 1.0f / sqrtf(red[0] / (float)DINNER + EPSF);
    yrow[i0] = g0 * scale * nwl[i0];
    yrow[i1] = g1 * scale * nwl[i1];
}

// ---------------------------------------------------------------- fusion: build comb = [fwd, unflip(bwd)]
__global__ __launch_bounds__(256) void concat_kernel(
    const float* __restrict__ u0, const float* __restrict__ u1, float* __restrict__ comb) {
    int row = blockIdx.x;
    int tid = threadIdx.x;
    int b = row >> 10, t = row & 1023;
    comb[(size_t)row * 512 + tid] = u0[(size_t)row * DMODEL + tid];
    comb[(size_t)row * 512 + 256 + tid] = u1[((size_t)(b << 10) + (1023 - t)) * DMODEL + tid];
}

// ---------------------------------------------------------------- fusion gates + LayerNorm
__global__ __launch_bounds__(256) void fusion_ln2_kernel(
    const float* __restrict__ comb, const float* __restrict__ gate,
    const float* __restrict__ fb, const float* __restrict__ lnw,
    const float* __restrict__ lnb, float* __restrict__ out) {
    int row = blockIdx.x;
    int tid = threadIdx.x;
    float f  = comb[(size_t)row * 512 + tid];
    float bw = comb[(size_t)row * 512 + 256 + tid];
    float g0 = sigmoidf_(gate[(size_t)row * 512 + tid] + fb[tid]);
    float g1 = sigmoidf_(gate[(size_t)row * 512 + 256 + tid] + fb[256 + tid]);
    float fused = g0 * f + g1 * bw;
    __shared__ float red[256];
    red[tid] = fused;
    __syncthreads();
    for (int s = 128; s > 0; s >>= 1) {
        if (tid < s) red[tid] += red[tid + s];
        __syncthreads();
    }
    float mu = red[0] / (float)DMODEL;
    __syncthreads();
    float d = fused - mu;
    red[tid] = d * d;
    __syncthreads();
    for (int s = 128; s > 0; s >>= 1) {
        if (tid < s) red[tid] += red[tid + s];
        __syncthreads();
    }
    float var = red[0] / (float)DMODEL;
    out[(size_t)row * DMODEL + tid] = d * (1.0f / sqrtf(var + EPSF)) * lnw[tid] + lnb[tid];
}

// ---------------------------------------------------------------- launch
extern "C" void kernel_launch(void* const* d_in, const int* in_sizes, int n_in,
                              void* d_out, int out_size, void* d_ws, size_t ws_size,
                              hipStream_t stream) {
    const int*   ids  = (const int*)d_in[0];
    const float* mask = (const float*)d_in[1];
    const float* tok  = (const float*)d_in[2];
    const float* pos  = (const float*)d_in[3];
    const float* inw  = (const float*)d_in[4];
    const float* cw   = (const float*)d_in[5];
    const float* cb   = (const float*)d_in[6];
    const float* dtb  = (const float*)d_in[7];
    const float* alog = (const float*)d_in[8];
    const float* dpar = (const float*)d_in[9];
    const float* nw   = (const float*)d_in[10];
    const float* ow   = (const float*)d_in[11];
    const float* fw   = (const float*)d_in[12];
    const float* fb   = (const float*)d_in[13];
    const float* lnw  = (const float*)d_in[14];
    const float* lnb  = (const float*)d_in[15];

    float* ws   = (float*)d_ws;
    float* ubuf = ws;                                        // 2*2048*256
    float* zbuf = ubuf + (size_t)2 * ROWS * DMODEL;          // 2*2048*512
    float* xbc  = zbuf + (size_t)2 * ROWS * DINNER;          // 2*2048*648
    float* xc   = xbc  + (size_t)2 * ROWS * XBCW;            // 2*2048*640
    float* dts  = xc   + (size_t)2 * ROWS * CONVDIM;         // 2*2048*8
    float* ybuf = dts  + (size_t)2 * ROWS * NHEADS;          // 2*2048*512
    // overlays (regions dead at time of use):
    float* H    = xbc;                                       // 32*16*4096 (xbc dead after conv)
    float* cumb = xbc + (size_t)32 * NC * 4096;              // 32*1024
    float* comb = xc;                                        // 2048*512 (xc dead after last scan)
    float* gate = xc + (size_t)ROWS * 512;                   // 2048*512

    embed_kernel<<<ROWS, DMODEL, 0, stream>>>(ids, mask, tok, pos, ubuf, ubuf + (size_t)ROWS * DMODEL);

    for (int layer = 0; layer < 2; ++layer) {
        dim3 g1(ROWS / 128, (DINPROJ + 127) / 128, 2);
        gemm128<<<g1, 256, 0, stream>>>(ubuf, inw + (size_t)layer * DINPROJ * DMODEL,
                                        zbuf, xbc,
                                        ROWS, DINPROJ, DMODEL, DINNER, DINNER, XBCW,
                                        (long)ROWS * DMODEL, (long)2 * DINPROJ * DMODEL,
                                        (long)ROWS * DINNER, (long)ROWS * XBCW);
        conv_dt_kernel<<<dim3(ROWS, 2), 256, 0, stream>>>(xbc, xc, dts, cw, cb, dtb, layer);
        scan_chunk_kernel<<<32 * NC, 64, 0, stream>>>(xc, dts, ybuf, alog, dpar, H, cumb, layer);
        carry_kernel<<<32, 256, 0, stream>>>(H, cumb);
        fix_kernel<<<32 * (NC - 1), 64, 0, stream>>>(xc, ybuf, H, cumb);
        gate_rms_kernel<<<dim3(ROWS, 2), 256, 0, stream>>>(ybuf, zbuf, nw, layer);
        dim3 g2(ROWS / BM, DMODEL / BN, 2);
        gemm_nt<<<g2, 256, 0, stream>>>(ybuf, ow + (size_t)layer * DMODEL * DINNER,
                                        ubuf, ubuf,
                                        ROWS, DMODEL, DINNER, DMODEL, DMODEL, DMODEL,
                                        (long)ROWS * DINNER, (long)2 * DMODEL * DINNER,
                                        (long)ROWS * DMODEL, (long)ROWS * DMODEL);
    }

    concat_kernel<<<ROWS, 256, 0, stream>>>(ubuf, ubuf + (size_t)ROWS * DMODEL, comb);
    dim3 g3(ROWS / BM, 512 / BN, 1);
    gemm_nt<<<g3, 256, 0, stream>>>(comb, fw, gate, gate,
                                    ROWS, 512, 512, 512, 512, 512,
                                    0L, 0L, 0L, 0L);
    fusion_ln2_kernel<<<ROWS, 256, 0, stream>>>(comb, gate, fb, lnw, lnb, (float*)d_out);
}

// Round 4
// 410.233 us; speedup vs baseline: 1.3501x; 1.3501x over previous
//
#include <hip/hip_runtime.h>
#include <cstddef>

#define LSEQ    1024
#define DMODEL  256
#define DINNER  512
#define DSTATE  64
#define NHEADS  8
#define HEADDIM 64
#define CONVDIM 640
#define DINPROJ 1160
#define ROWS    2048   // B * L
#define EPSF    1e-5f
#define NC      16     // chunks per sequence
#define LC      64     // chunk length
#define XBCW    648    // xBC (640) + raw dt (8)

// weight-pair buffer geometry (element counts)
#define WIN  593920    // 2 dirs * 1160 * 256 (one layer of in_w)
#define WOUT 262144    // 2 dirs * 256 * 512  (one layer of out_w)
#define WF   262144    // 512 * 512           (fusion_w)
#define PSI  296960    // 1160*256 per (dir,layer) slice of in_w
#define PSO  131072    // 256*512  per (dir,layer) slice of out_w

typedef _Float16 f16;
typedef f16   v8h __attribute__((ext_vector_type(8)));
typedef float v4f __attribute__((ext_vector_type(4)));
#define MFMA16(a, b, c) __builtin_amdgcn_mfma_f32_16x16x32_f16(a, b, c, 0, 0, 0)

__device__ __forceinline__ float sigmoidf_(float x) { return 1.0f / (1.0f + expf(-x)); }
__device__ __forceinline__ float siluf_(float x)    { return x / (1.0f + expf(-x)); }
__device__ __forceinline__ float softplusf_(float x) {
    return x > 0.0f ? x + log1pf(expf(-x)) : log1pf(expf(x));
}
__device__ __forceinline__ void split16(float v, f16& h, f16& l) {
    h = (f16)v;                         // RN; v - h exact in fp32
    l = (f16)((v - (float)h) * 4096.0f); // residual beyond pair <= 2^-24 |v|
}

// ---------------------------------------------------------------- embedding -> f16 pairs (fwd + time-flipped)
__global__ __launch_bounds__(256) void embed_kernel(
    const int* __restrict__ ids, const float* __restrict__ mask,
    const float* __restrict__ tok, const float* __restrict__ pos,
    f16* __restrict__ uh, f16* __restrict__ ul) {
    int row = blockIdx.x;            // b*1024 + t
    int d = threadIdx.x;
    int b = row >> 10, t = row & 1023;
    int id = ids[row];
    float v = tok[(size_t)id * DMODEL + d] + pos[(size_t)t * DMODEL + d];
    v *= mask[row];
    f16 h, l; split16(v, h, l);
    size_t fwd = (size_t)row * DMODEL + d;
    size_t bwd = (size_t)ROWS * DMODEL + ((size_t)(b << 10) + (1023 - t)) * DMODEL + d;
    uh[fwd] = h; ul[fwd] = l;
    uh[bwd] = h; ul[bwd] = l;
}

// ---------------------------------------------------------------- weight fp32 -> f16 pair conversion (per layer)
__global__ __launch_bounds__(256) void wconv_kernel(
    const float* __restrict__ inw, const float* __restrict__ ow, const float* __restrict__ fw,
    f16* __restrict__ wb, int layer, int total) {
    int idx = (blockIdx.x * 256 + threadIdx.x) * 4;
#pragma unroll
    for (int e = idx; e < idx + 4; ++e) {
        if (e >= total) break;
        float v; f16 *dh, *dl; int off;
        if (e < WIN) {
            int d = e / PSI, r = e - d * PSI;
            v = inw[(size_t)(d * 2 + layer) * PSI + r];
            dh = wb; dl = wb + WIN; off = e;
        } else if (e < WIN + WOUT) {
            int e2 = e - WIN;
            int d = e2 / PSO, r = e2 - d * PSO;
            v = ow[(size_t)(d * 2 + layer) * PSO + r];
            dh = wb + 2 * WIN; dl = dh + WOUT; off = e2;
        } else {
            int e3 = e - WIN - WOUT;
            v = fw[e3];
            dh = wb + 2 * WIN + 2 * WOUT; dl = dh + WF; off = e3;
        }
        f16 h, l; split16(v, h, l);
        dh[off] = h; dl[off] = l;
    }
}

// ---------------------------------------------------------------- f16x3 MFMA GEMM: C[M,N] = A[M,K] * W[N,K]^T
// A,W given as exact f16 (hi, lo*2^12) pairs. 64x64 tile / block, 4 waves of 32x32.
__global__ __launch_bounds__(256) void gemm_f16x3(
    const f16* __restrict__ Ah, const f16* __restrict__ Al, long sA,
    const f16* __restrict__ Wh, const f16* __restrict__ Wl, long sW,
    int N, int K, int Nsplit,
    float* __restrict__ O0, int ld0, long sO0,
    float* __restrict__ O1, int ld1, long sO1,
    f16* __restrict__ Ph, f16* __restrict__ Pl, int ldP, long sP,
    int has32, int haspair) {
    int dir = blockIdx.z;
    Ah += (size_t)dir * sA; Al += (size_t)dir * sA;
    Wh += (size_t)dir * sW; Wl += (size_t)dir * sW;
    if (has32)  { O0 += (size_t)dir * sO0; O1 += (size_t)dir * sO1; }
    if (haspair){ Ph += (size_t)dir * sP;  Pl += (size_t)dir * sP; }

    __shared__ f16 sm[4 * 64 * 72];      // Ah | Al | Wh | Wl tiles, 64 rows x 64 k, pitch 72
    f16* As_h = sm;
    f16* As_l = sm + 64 * 72;
    f16* Ws_h = sm + 2 * 64 * 72;
    f16* Ws_l = sm + 3 * 64 * 72;

    int tid = threadIdx.x;
    int m0 = blockIdx.x * 64, n0 = blockIdx.y * 64;
    int srow = tid >> 2, sseg = tid & 3;           // staging: 64 rows x 4 segs of 16 halves
    int lane = tid & 63, w = tid >> 6;
    int wrow = (w >> 1) * 32, wcol = (w & 1) * 32;
    int q = lane >> 4, r16 = lane & 15;
    bool wok = (n0 + srow) < N;

    v4f accM[2][2], accX[2][2];
#pragma unroll
    for (int i = 0; i < 2; ++i)
#pragma unroll
        for (int j = 0; j < 2; ++j) { accM[i][j] = (v4f)0.0f; accX[i][j] = (v4f)0.0f; }

    for (int k0 = 0; k0 < K; k0 += 64) {
        size_t aoff = (size_t)(m0 + srow) * K + k0 + sseg * 16;
        float4 ah0 = *(const float4*)&Ah[aoff];
        float4 ah1 = *(const float4*)&Ah[aoff + 8];
        float4 al0 = *(const float4*)&Al[aoff];
        float4 al1 = *(const float4*)&Al[aoff + 8];
        float4 wh0 = make_float4(0.f,0.f,0.f,0.f), wh1 = wh0, wl0 = wh0, wl1 = wh0;
        if (wok) {
            size_t woff = (size_t)(n0 + srow) * K + k0 + sseg * 16;
            wh0 = *(const float4*)&Wh[woff];
            wh1 = *(const float4*)&Wh[woff + 8];
            wl0 = *(const float4*)&Wl[woff];
            wl1 = *(const float4*)&Wl[woff + 8];
        }
        __syncthreads();                 // previous iteration's reads done
        int d = srow * 72 + sseg * 16;
        *(float4*)&As_h[d] = ah0; *(float4*)&As_h[d + 8] = ah1;
        *(float4*)&As_l[d] = al0; *(float4*)&As_l[d + 8] = al1;
        *(float4*)&Ws_h[d] = wh0; *(float4*)&Ws_h[d + 8] = wh1;
        *(float4*)&Ws_l[d] = wl0; *(float4*)&Ws_l[d + 8] = wl1;
        __syncthreads();

#pragma unroll
        for (int ks = 0; ks < 64; ks += 32) {
            v8h fa_h[2], fa_l[2], fb_h[2], fb_l[2];
#pragma unroll
            for (int i = 0; i < 2; ++i) {
                int ra = (wrow + i * 16 + r16) * 72 + ks + q * 8;
                int rb = (wcol + i * 16 + r16) * 72 + ks + q * 8;
                fa_h[i] = *(const v8h*)&As_h[ra];
                fa_l[i] = *(const v8h*)&As_l[ra];
                fb_h[i] = *(const v8h*)&Ws_h[rb];
                fb_l[i] = *(const v8h*)&Ws_l[rb];
            }
#pragma unroll
            for (int i = 0; i < 2; ++i)
#pragma unroll
                for (int j = 0; j < 2; ++j) {
                    accM[i][j] = MFMA16(fa_h[i], fb_h[j], accM[i][j]);
                    accX[i][j] = MFMA16(fa_h[i], fb_l[j], accX[i][j]);
                    accX[i][j] = MFMA16(fa_l[i], fb_h[j], accX[i][j]);
                }
        }
    }

    const float cs = 1.0f / 4096.0f;
#pragma unroll
    for (int i = 0; i < 2; ++i)
#pragma unroll
        for (int j = 0; j < 2; ++j) {
            int nn = n0 + wcol + j * 16 + r16;
            if (nn < N) {
#pragma unroll
                for (int r = 0; r < 4; ++r) {
                    float v = accM[i][j][r] + accX[i][j][r] * cs;
                    int mm = m0 + wrow + i * 16 + q * 4 + r;
                    if (has32) {
                        if (nn < Nsplit) O0[(size_t)mm * ld0 + nn] = v;
                        else             O1[(size_t)mm * ld1 + (nn - Nsplit)] = v;
                    }
                    if (haspair) {
                        f16 h, l; split16(v, h, l);
                        Ph[(size_t)mm * ldP + nn] = h;
                        Pl[(size_t)mm * ldP + nn] = l;
                    }
                }
            }
        }
}

// ---------------------------------------------------------------- depthwise causal conv(4) + SiLU, plus softplus(dt)
__global__ __launch_bounds__(256) void conv_dt_kernel(
    const float* __restrict__ xbc, float* __restrict__ xc, float* __restrict__ dts,
    const float* __restrict__ cw, const float* __restrict__ cb,
    const float* __restrict__ dtb, int layer) {
    int row = blockIdx.x;            // b*1024+t
    int dir = blockIdx.y;
    int b = row >> 10, t = row & 1023;
    const float* xd = xbc + (size_t)dir * ROWS * XBCW;
    int pi = dir * 2 + layer;
    const float* cwl = cw + (size_t)pi * CONVDIM * 4;
    const float* cbl = cb + (size_t)pi * CONVDIM;
    const float* dtbl = dtb + pi * NHEADS;
    for (int c = threadIdx.x; c < CONVDIM + NHEADS; c += 256) {
        if (c < CONVDIM) {
            float acc = cbl[c];
#pragma unroll
            for (int k = 0; k < 4; ++k) {
                int tt = t - 3 + k;
                if (tt >= 0)
                    acc = fmaf(xd[(size_t)((b << 10) + tt) * XBCW + c], cwl[c * 4 + k], acc);
            }
            xc[((size_t)dir * ROWS + row) * CONVDIM + c] = siluf_(acc);
        } else {
            int hh = c - CONVDIM;
            dts[((size_t)dir * ROWS + row) * NHEADS + hh] =
                softplusf_(xd[(size_t)row * XBCW + CONVDIM + hh] + dtbl[hh]);
        }
    }
}

// ---------------------------------------------------------------- S1: local chunk scan (from zero state)
__global__ __launch_bounds__(64) void scan_chunk_kernel(
    const float* __restrict__ xc, const float* __restrict__ dts,
    float* __restrict__ y, const float* __restrict__ Alog, const float* __restrict__ Dp,
    float* __restrict__ H, float* __restrict__ cumb, int layer) {
    __shared__ float sBC[LC * 128];
    __shared__ float sX[LC * 64];
    int blk = blockIdx.x;
    int u = blk >> 4, c = blk & 15;
    int dir = u >> 4, b = (u >> 3) & 1, h = u & 7;
    int p = threadIdx.x;
    int pi = dir * 2 + layer;
    float Av = -expf(Alog[pi * NHEADS + h]);
    float Dv = Dp[pi * NHEADS + h];
    const float* xcd = xc + (size_t)dir * ROWS * CONVDIM;
    const float* dtd = dts + (size_t)dir * ROWS * NHEADS;
    float* yd = y + (size_t)dir * ROWS * DINNER;
    int t0 = c * LC, base = b << 10;

    float dt_l = dtd[(size_t)(base + t0 + p) * NHEADS + h];
    float dA_l = expf(dt_l * Av);
    float cum_l = dA_l;
#pragma unroll
    for (int off = 1; off < 64; off <<= 1) {
        float o = __shfl_up(cum_l, off);
        if (p >= off) cum_l *= o;
    }
    cumb[(u << 10) + t0 + p] = cum_l;

#pragma unroll
    for (int j = 0; j < 32; ++j) {
        int f4 = j * 64 + p;
        int trow = f4 >> 5, col4 = f4 & 31;
        float4 v = *(const float4*)&xcd[(size_t)(base + t0 + trow) * CONVDIM + DINNER + col4 * 4];
        *(float4*)&sBC[trow * 128 + col4 * 4] = v;
    }
#pragma unroll
    for (int j = 0; j < 16; ++j) {
        int f4 = j * 64 + p;
        int trow = f4 >> 4, col4 = f4 & 15;
        float4 v = *(const float4*)&xcd[(size_t)(base + t0 + trow) * CONVDIM + h * HEADDIM + col4 * 4];
        *(float4*)&sX[trow * 64 + col4 * 4] = v;
    }
    __syncthreads();

    float hreg[DSTATE];
#pragma unroll
    for (int n = 0; n < DSTATE; ++n) hreg[n] = 0.f;

#pragma unroll 2
    for (int tt = 0; tt < LC; ++tt) {
        float dtv = __shfl(dt_l, tt);
        float dA  = __shfl(dA_l, tt);
        float xv = sX[tt * 64 + p];
        float coef = dtv * xv;
        const float* Bsr = &sBC[tt * 128];
        const float* Csr = Bsr + 64;
        float y0 = 0.f, y1 = 0.f, y2 = 0.f, y3 = 0.f;
#pragma unroll
        for (int n = 0; n < DSTATE; n += 4) {
            float4 b4 = *(const float4*)&Bsr[n];
            float4 c4 = *(const float4*)&Csr[n];
            hreg[n]     = fmaf(hreg[n],     dA, coef * b4.x); y0 = fmaf(hreg[n],     c4.x, y0);
            hreg[n + 1] = fmaf(hreg[n + 1], dA, coef * b4.y); y1 = fmaf(hreg[n + 1], c4.y, y1);
            hreg[n + 2] = fmaf(hreg[n + 2], dA, coef * b4.z); y2 = fmaf(hreg[n + 2], c4.z, y2);
            hreg[n + 3] = fmaf(hreg[n + 3], dA, coef * b4.w); y3 = fmaf(hreg[n + 3], c4.w, y3);
        }
        yd[(size_t)(base + t0 + tt) * DINNER + h * HEADDIM + p] = (y0 + y1) + (y2 + y3) + Dv * xv;
    }
    float* Hb = H + (size_t)blk * 4096 + p * 64;
#pragma unroll
    for (int n = 0; n < DSTATE; n += 4)
        *(float4*)&Hb[n] = make_float4(hreg[n], hreg[n + 1], hreg[n + 2], hreg[n + 3]);
}

// ---------------------------------------------------------------- S2: carry chain over chunks
__global__ __launch_bounds__(256) void carry_kernel(
    float* __restrict__ H, const float* __restrict__ cumb) {
    int u = blockIdx.x;
    int tid = threadIdx.x;
    float P[NC];
#pragma unroll
    for (int c = 0; c < NC; ++c) P[c] = cumb[(u << 10) + c * LC + (LC - 1)];
    float carry[16];
#pragma unroll
    for (int j = 0; j < 16; ++j) carry[j] = 0.f;
    for (int c = 0; c < NC; ++c) {
        float* Hb = H + (size_t)(u * NC + c) * 4096 + tid * 16;
        float Pc = P[c];
#pragma unroll
        for (int j = 0; j < 4; ++j) {
            float4 e = *(const float4*)&Hb[j * 4];
            *(float4*)&Hb[j * 4] = make_float4(carry[j*4], carry[j*4+1], carry[j*4+2], carry[j*4+3]);
            carry[j*4]     = fmaf(Pc, carry[j*4],     e.x);
            carry[j*4 + 1] = fmaf(Pc, carry[j*4 + 1], e.y);
            carry[j*4 + 2] = fmaf(Pc, carry[j*4 + 2], e.z);
            carry[j*4 + 3] = fmaf(Pc, carry[j*4 + 3], e.w);
        }
    }
}

// ---------------------------------------------------------------- S3: y[t] += cum[t] * (C_t . h_in)
__global__ __launch_bounds__(64) void fix_kernel(
    const float* __restrict__ xc, float* __restrict__ y,
    const float* __restrict__ H, const float* __restrict__ cumb) {
    __shared__ float sC[LC * 64];
    int blk = blockIdx.x;
    int u = blk / (NC - 1);
    int c = blk % (NC - 1) + 1;
    int dir = u >> 4, b = (u >> 3) & 1, h = u & 7;
    int p = threadIdx.x;
    const float* xcd = xc + (size_t)dir * ROWS * CONVDIM;
    float* yd = y + (size_t)dir * ROWS * DINNER;
    int t0 = c * LC, base = b << 10;
    float cum_l = cumb[(u << 10) + t0 + p];
#pragma unroll
    for (int j = 0; j < 16; ++j) {
        int f4 = j * 64 + p;
        int trow = f4 >> 4, col4 = f4 & 15;
        float4 v = *(const float4*)&xcd[(size_t)(base + t0 + trow) * CONVDIM + DINNER + DSTATE + col4 * 4];
        *(float4*)&sC[trow * 64 + col4 * 4] = v;
    }
    const float* Hb = H + (size_t)(u * NC + c) * 4096 + p * 64;
    float hin[DSTATE];
#pragma unroll
    for (int n = 0; n < DSTATE; n += 4) {
        float4 v = *(const float4*)&Hb[n];
        hin[n] = v.x; hin[n + 1] = v.y; hin[n + 2] = v.z; hin[n + 3] = v.w;
    }
    __syncthreads();
#pragma unroll 2
    for (int tt = 0; tt < LC; ++tt) {
        float cumt = __shfl(cum_l, tt);
        const float* Cs = &sC[tt * 64];
        float y0 = 0.f, y1 = 0.f, y2 = 0.f, y3 = 0.f;
#pragma unroll
        for (int n = 0; n < DSTATE; n += 4) {
            y0 = fmaf(hin[n],     Cs[n],     y0);
            y1 = fmaf(hin[n + 1], Cs[n + 1], y1);
            y2 = fmaf(hin[n + 2], Cs[n + 2], y2);
            y3 = fmaf(hin[n + 3], Cs[n + 3], y3);
        }
        size_t yi = (size_t)(base + t0 + tt) * DINNER + h * HEADDIM + p;
        yd[yi] += cumt * ((y0 + y1) + (y2 + y3));
    }
}

// ---------------------------------------------------------------- y*silu(z), RMSNorm*nw -> f16 pairs
__global__ __launch_bounds__(256) void gate_rms_kernel(
    const float* __restrict__ y, const float* __restrict__ zbuf,
    const float* __restrict__ nw, f16* __restrict__ yh, f16* __restrict__ yl, int layer) {
    int row = blockIdx.x;
    int dir = blockIdx.y;
    const float* zrow = zbuf + ((size_t)dir * ROWS + row) * DINNER;
    const float* yrow = y + ((size_t)dir * ROWS + row) * DINNER;
    f16* yhr = yh + ((size_t)dir * ROWS + row) * DINNER;
    f16* ylr = yl + ((size_t)dir * ROWS + row) * DINNER;
    const float* nwl = nw + (dir * 2 + layer) * DINNER;
    int tid = threadIdx.x;
    int i0 = tid, i1 = tid + 256;
    float g0 = yrow[i0] * siluf_(zrow[i0]);
    float g1 = yrow[i1] * siluf_(zrow[i1]);
    __shared__ float red[256];
    red[tid] = fmaf(g0, g0, g1 * g1);
    __syncthreads();
    for (int s = 128; s > 0; s >>= 1) {
        if (tid < s) red[tid] += red[tid + s];
        __syncthreads();
    }
    float scale = 1.0f / sqrtf(red[0] / (float)DINNER + EPSF);
    float v0 = g0 * scale * nwl[i0];
    float v1 = g1 * scale * nwl[i1];
    f16 h, l;
    split16(v0, h, l); yhr[i0] = h; ylr[i0] = l;
    split16(v1, h, l); yhr[i1] = h; ylr[i1] = l;
}

// ---------------------------------------------------------------- build comb pairs = [fwd, unflip(bwd)]
__global__ __launch_bounds__(256) void concat_kernel(
    const f16* __restrict__ uh, const f16* __restrict__ ul,
    f16* __restrict__ combh, f16* __restrict__ combl) {
    int row = blockIdx.x;
    int tid = threadIdx.x;
    int b = row >> 10, t = row & 1023;
    size_t fwd = (size_t)row * DMODEL + tid;
    size_t bwd = (size_t)ROWS * DMODEL + ((size_t)(b << 10) + (1023 - t)) * DMODEL + tid;
    combh[(size_t)row * 512 + tid] = uh[fwd];
    combl[(size_t)row * 512 + tid] = ul[fwd];
    combh[(size_t)row * 512 + 256 + tid] = uh[bwd];
    combl[(size_t)row * 512 + 256 + tid] = ul[bwd];
}

// ---------------------------------------------------------------- fusion gates + LayerNorm
__global__ __launch_bounds__(256) void fusion_ln2_kernel(
    const float* __restrict__ u32, const float* __restrict__ gate,
    const float* __restrict__ fb, const float* __restrict__ lnw,
    const float* __restrict__ lnb, float* __restrict__ out) {
    int row = blockIdx.x;
    int b = row >> 10, t = row & 1023;
    int tid = threadIdx.x;
    float f  = u32[(size_t)row * DMODEL + tid];
    float bw = u32[(size_t)ROWS * DMODEL + ((size_t)(b << 10) + (1023 - t)) * DMODEL + tid];
    float g0 = sigmoidf_(gate[(size_t)row * 512 + tid] + fb[tid]);
    float g1 = sigmoidf_(gate[(size_t)row * 512 + 256 + tid] + fb[256 + tid]);
    float fused = g0 * f + g1 * bw;
    __shared__ float red[256];
    red[tid] = fused;
    __syncthreads();
    for (int s = 128; s > 0; s >>= 1) {
        if (tid < s) red[tid] += red[tid + s];
        __syncthreads();
    }
    float mu = red[0] / (float)DMODEL;
    __syncthreads();
    float d = fused - mu;
    red[tid] = d * d;
    __syncthreads();
    for (int s = 128; s > 0; s >>= 1) {
        if (tid < s) red[tid] += red[tid + s];
        __syncthreads();
    }
    float var = red[0] / (float)DMODEL;
    out[(size_t)row * DMODEL + tid] = d * (1.0f / sqrtf(var + EPSF)) * lnw[tid] + lnb[tid];
}

// ---------------------------------------------------------------- launch
extern "C" void kernel_launch(void* const* d_in, const int* in_sizes, int n_in,
                              void* d_out, int out_size, void* d_ws, size_t ws_size,
                              hipStream_t stream) {
    const int*   ids  = (const int*)d_in[0];
    const float* mask = (const float*)d_in[1];
    const float* tok  = (const float*)d_in[2];
    const float* pos  = (const float*)d_in[3];
    const float* inw  = (const float*)d_in[4];
    const float* cw   = (const float*)d_in[5];
    const float* cb   = (const float*)d_in[6];
    const float* dtb  = (const float*)d_in[7];
    const float* alog = (const float*)d_in[8];
    const float* dpar = (const float*)d_in[9];
    const float* nw   = (const float*)d_in[10];
    const float* ow   = (const float*)d_in[11];
    const float* fw   = (const float*)d_in[12];
    const float* fb   = (const float*)d_in[13];
    const float* lnw  = (const float*)d_in[14];
    const float* lnb  = (const float*)d_in[15];

    float* ws = (float*)d_ws;
    // float-unit offsets
    float* zbuf = ws;                      // 2,097,152 f  (z, fp32)
    float* xbc  = ws + 2097152;            // 2,654,208 f  (in_proj xBC+dtraw fp32; later H + cumb overlay)
    float* xc   = ws + 4751360;            // 2,621,440 f  (conv out fp32; later yh/yl pairs, then gate)
    float* dts  = ws + 7372800;            //    32,768 f
    float* ybuf = ws + 7405568;            // 2,097,152 f  (scan y fp32; later u_fp32 + comb pairs)
    f16*   uh   = (f16*)(ws + 9502720);    // 1,048,576 h
    f16*   ul   = (f16*)(ws + 10027008);   // 1,048,576 h
    f16*   wb   = (f16*)(ws + 10551296);   // 2,236,416 h (weight pairs)
    // overlays
    float* H    = xbc;                     // 512 * 4096 f
    float* cumb = xbc + 2097152;           // 32,768 f
    f16*   yh   = (f16*)xc;                // 2,097,152 h
    f16*   yl   = (f16*)(xc + 1048576);    // 2,097,152 h
    float* gate = xc;                      // 1,048,576 f (fusion time; yh/yl dead)
    float* u32  = ybuf;                    // 1,048,576 f (out_proj fp32)
    f16*   combh = (f16*)(ybuf + 1048576); // 1,048,576 h
    f16*   combl = (f16*)(ybuf + 1572864); // 1,048,576 h
    // weight-pair sub-pointers
    f16* wih = wb;               f16* wil = wb + WIN;
    f16* woh = wb + 2 * WIN;     f16* wol = wb + 2 * WIN + WOUT;
    f16* wfh = wb + 2 * WIN + 2 * WOUT;
    f16* wfl = wfh + WF;

    embed_kernel<<<ROWS, DMODEL, 0, stream>>>(ids, mask, tok, pos, uh, ul);

    for (int layer = 0; layer < 2; ++layer) {
        int wtot = WIN + WOUT + (layer == 1 ? WF : 0);
        wconv_kernel<<<(wtot + 1023) / 1024, 256, 0, stream>>>(inw, ow, fw, wb, layer, wtot);

        // in_proj: A=(uh,ul) [dir][2048][256], W pairs, N=1160 -> zbuf(512) + xbc(648)
        dim3 g1(ROWS / 64, (DINPROJ + 63) / 64, 2);
        gemm_f16x3<<<g1, 256, 0, stream>>>(
            uh, ul, (long)ROWS * DMODEL,
            wih, wil, (long)PSI,
            DINPROJ, DMODEL, DINNER,
            zbuf, DINNER, (long)ROWS * DINNER,
            xbc, XBCW, (long)ROWS * XBCW,
            (f16*)nullptr, (f16*)nullptr, 0, 0L,
            1, 0);

        conv_dt_kernel<<<dim3(ROWS, 2), 256, 0, stream>>>(xbc, xc, dts, cw, cb, dtb, layer);
        scan_chunk_kernel<<<32 * NC, 64, 0, stream>>>(xc, dts, ybuf, alog, dpar, H, cumb, layer);
        carry_kernel<<<32, 256, 0, stream>>>(H, cumb);
        fix_kernel<<<32 * (NC - 1), 64, 0, stream>>>(xc, ybuf, H, cumb);
        gate_rms_kernel<<<dim3(ROWS, 2), 256, 0, stream>>>(ybuf, zbuf, nw, yh, yl, layer);

        // out_proj: A=(yh,yl) [dir][2048][512], N=256 -> u32 fp32 + (uh,ul) pairs
        dim3 g2(ROWS / 64, DMODEL / 64, 2);
        gemm_f16x3<<<g2, 256, 0, stream>>>(
            yh, yl, (long)ROWS * DINNER,
            woh, wol, (long)PSO,
            DMODEL, DINNER, DMODEL,
            u32, DMODEL, (long)ROWS * DMODEL,
            u32, DMODEL, (long)ROWS * DMODEL,
            uh, ul, DMODEL, (long)ROWS * DMODEL,
            1, 1);
    }

    concat_kernel<<<ROWS, 256, 0, stream>>>(uh, ul, combh, combl);

    // fusion: A=(combh,combl) [2048][512], N=512 -> gate fp32
    dim3 g3(ROWS / 64, 512 / 64, 1);
    gemm_f16x3<<<g3, 256, 0, stream>>>(
        combh, combl, 0L,
        wfh, wfl, 0L,
        512, 512, 512,
        gate, 512, 0L,
        gate, 512, 0L,
        (f16*)nullptr, (f16*)nullptr, 0, 0L,
        1, 0);

    fusion_ln2_kernel<<<ROWS, 256, 0, stream>>>(u32, gate, fb, lnw, lnb, (float*)d_out);
}